// Round 1
// baseline (121.873 us; speedup 1.0000x reference)
//
#include <hip/hip_runtime.h>

#define H    300
#define MID  100
#define NN   1024
#define NP1  1025

static __device__ __forceinline__ float sigmoid_fast(float t) {
    // sigma(t) = 1 / (1 + e^{-t}) = 1 / (1 + 2^{-t*log2(e)})
    const float NLOG2E = -1.4426950408889634f;
    return __builtin_amdgcn_rcpf(1.0f + __builtin_amdgcn_exp2f(t * NLOG2E));
}

// Kernel A: compute s1b[i][m] = b1[m] + sentence[i,:] . W1[m, :H]      (1024 x 100)
//           s2T[m][j]         = pm[j,:]       . W1[m, H:]               (100 x 1025, transposed)
// Blocks 0..1023 -> s1 rows; blocks 1024..2048 -> s2 columns (j = b-1024, pm[0]=0).
__global__ __launch_bounds__(128) void precompute_kernel(
    const float* __restrict__ sentence,
    const float* __restrict__ W1,
    const float* __restrict__ b1,
    float* __restrict__ s1b,
    float* __restrict__ s2T)
{
    __shared__ __align__(16) float row[H];
    const int b = blockIdx.x;
    const int tid = threadIdx.x;
    const bool first = (b < NN);
    const int j = b - NN;

    const float* src;
    if (first) {
        src = sentence + (long)b * H;
    } else {
        if (j == 0) {
            if (tid < MID) s2T[(long)tid * NP1] = 0.0f;  // pm[0] = zeros -> dot = 0
            return;
        }
        src = sentence + (long)(j - 1) * H;
    }
    for (int h = tid; h < H; h += 128) row[h] = src[h];
    __syncthreads();

    const int m = tid;
    if (m < MID) {
        const float* w = W1 + (long)m * (2 * H) + (first ? 0 : H);
        const float4* w4 = (const float4*)w;     // both halves 16B aligned (2400B / 1200B offsets)
        const float4* r4 = (const float4*)row;
        float acc = 0.0f;
        #pragma unroll 5
        for (int h = 0; h < H / 4; ++h) {
            float4 a = r4[h], ww = w4[h];
            acc += a.x * ww.x + a.y * ww.y + a.z * ww.z + a.w * ww.w;
        }
        if (first) s1b[b * MID + m] = acc + b1[m];
        else       s2T[(long)m * NP1 + j] = acc;
    }
}

// Kernel B: one block per row i. scores[i][j] = b2 + sum_m W2[m]*sigmoid(s1b[i][m]+s2T[m][j]).
// Then: loss partial (|score - onehot|) -> atomicAdd to out[0]; row softmax -> out[1 + i*1025 + j].
__global__ __launch_bounds__(256) void main_kernel(
    const float* __restrict__ s1b,
    const float* __restrict__ s2T,
    const float* __restrict__ W2,
    const float* __restrict__ b2,
    const int*   __restrict__ target,
    float* __restrict__ out)
{
    __shared__ float s1[MID];
    __shared__ float w2[MID];
    __shared__ float sc[NP1];
    __shared__ float red[256];

    const int i = blockIdx.x;
    const int tid = threadIdx.x;
    const float LOG2E = 1.4426950408889634f;

    if (tid < MID) {
        s1[tid] = s1b[i * MID + tid];
        w2[tid] = W2[tid];
    }
    const float b2v = b2[0];
    __syncthreads();

    // main pairwise loop: 4 columns per thread (j = tid + 256k), coalesced s2T reads
    float acc0 = 0.f, acc1 = 0.f, acc2 = 0.f, acc3 = 0.f;
    for (int m = 0; m < MID; ++m) {
        const float a = s1[m];
        const float w = w2[m];
        const float* p = s2T + (long)m * NP1;
        float x0 = p[tid];
        float x1 = p[tid + 256];
        float x2 = p[tid + 512];
        float x3 = p[tid + 768];
        acc0 += w * sigmoid_fast(a + x0);
        acc1 += w * sigmoid_fast(a + x1);
        acc2 += w * sigmoid_fast(a + x2);
        acc3 += w * sigmoid_fast(a + x3);
    }
    const float sc0 = acc0 + b2v;
    const float sc1 = acc1 + b2v;
    const float sc2 = acc2 + b2v;
    const float sc3 = acc3 + b2v;
    sc[tid]       = sc0;
    sc[tid + 256] = sc1;
    sc[tid + 512] = sc2;
    sc[tid + 768] = sc3;

    // remainder column j = 1024: cooperative 100-wide dot
    if (tid < MID) {
        red[tid] = w2[tid] * sigmoid_fast(s1[tid] + s2T[(long)tid * NP1 + 1024]);
    }
    __syncthreads();
    if (tid == 0) {
        float s = 0.f;
        for (int m = 0; m < MID; ++m) s += red[m];
        sc[1024] = s + b2v;
    }
    __syncthreads();

    // ---- loss partial: sum |score - indicator| ----
    const int tgt = target[i];
    float ls = fabsf(sc0 - ((tid        == tgt) ? 1.f : 0.f))
             + fabsf(sc1 - ((tid + 256  == tgt) ? 1.f : 0.f))
             + fabsf(sc2 - ((tid + 512  == tgt) ? 1.f : 0.f))
             + fabsf(sc3 - ((tid + 768  == tgt) ? 1.f : 0.f));
    if (tid == 0) ls += fabsf(sc[1024] - ((1024 == tgt) ? 1.f : 0.f));
    red[tid] = ls;
    __syncthreads();
    for (int s = 128; s > 0; s >>= 1) {
        if (tid < s) red[tid] += red[tid + s];
        __syncthreads();
    }
    if (tid == 0) {
        atomicAdd(out, red[0] * (1.0f / ((float)NN * (float)NP1)));
    }
    __syncthreads();

    // ---- row max ----
    float ml = fmaxf(fmaxf(sc0, sc1), fmaxf(sc2, sc3));
    if (tid == 0) ml = fmaxf(ml, sc[1024]);
    red[tid] = ml;
    __syncthreads();
    for (int s = 128; s > 0; s >>= 1) {
        if (tid < s) red[tid] = fmaxf(red[tid], red[tid + s]);
        __syncthreads();
    }
    const float rowmax = red[0];
    __syncthreads();

    // ---- exp + sum ----
    const float e0 = __builtin_amdgcn_exp2f((sc0 - rowmax) * LOG2E);
    const float e1 = __builtin_amdgcn_exp2f((sc1 - rowmax) * LOG2E);
    const float e2 = __builtin_amdgcn_exp2f((sc2 - rowmax) * LOG2E);
    const float e3 = __builtin_amdgcn_exp2f((sc3 - rowmax) * LOG2E);
    float e4 = 0.f;
    if (tid == 0) e4 = __builtin_amdgcn_exp2f((sc[1024] - rowmax) * LOG2E);
    red[tid] = e0 + e1 + e2 + e3 + e4;
    __syncthreads();
    for (int s = 128; s > 0; s >>= 1) {
        if (tid < s) red[tid] += red[tid + s];
        __syncthreads();
    }
    const float inv = 1.0f / red[0];

    // ---- write softmax row ----
    float* orow = out + 1 + (long)i * NP1;
    orow[tid]       = e0 * inv;
    orow[tid + 256] = e1 * inv;
    orow[tid + 512] = e2 * inv;
    orow[tid + 768] = e3 * inv;
    if (tid == 0) orow[1024] = e4 * inv;
}

extern "C" void kernel_launch(void* const* d_in, const int* in_sizes, int n_in,
                              void* d_out, int out_size, void* d_ws, size_t ws_size,
                              hipStream_t stream) {
    const float* sentence = (const float*)d_in[0];
    const int*   target   = (const int*)  d_in[1];
    const float* W1       = (const float*)d_in[2];
    const float* b1       = (const float*)d_in[3];
    const float* W2       = (const float*)d_in[4];
    const float* b2       = (const float*)d_in[5];
    float* out = (float*)d_out;

    float* s1b = (float*)d_ws;              // 1024*100 floats
    float* s2T = s1b + NN * MID;            // 100*1025 floats (total ~820 KB)

    // zero the loss accumulator (d_out is re-poisoned to 0xAA before every launch)
    hipMemsetAsync(d_out, 0, sizeof(float), stream);

    precompute_kernel<<<NN + NP1, 128, 0, stream>>>(sentence, W1, b1, s1b, s2T);
    main_kernel<<<NN, 256, 0, stream>>>(s1b, s2T, W2, b2, target, out);
}